// Round 16
// baseline (238.574 us; speedup 1.0000x reference)
//
#include <hip/hip_runtime.h>
#include <hip/hip_fp16.h>

#define BB 2
#define SS 2048
#define DD 1024
#define HH 16
#define DKK 64
#define BHH (BB*HH)
#define MM (BB*SS)
#define EPSF 1e-5f

typedef _Float16 f16;
typedef _Float16 f16x4 __attribute__((ext_vector_type(4)));
typedef _Float16 f16x8 __attribute__((ext_vector_type(8)));
typedef float f32x4 __attribute__((ext_vector_type(4)));

// XOR swizzle for 128-byte LDS rows: permutes 16B slots, kills stride-128B bank conflicts
__device__ __forceinline__ int swz128(int row, int byteInRow) {
    return row * 128 + (byteInRow ^ ((row & 7) << 4));
}

// global -> LDS direct (16B per lane). LDS dest is wave-uniform base + lane*16.
__device__ __forceinline__ void gl_lds16(const f16* g, f16* l) {
    __builtin_amdgcn_global_load_lds((const __attribute__((address_space(1))) void*)g,
                                     (__attribute__((address_space(3))) void*)l, 16, 0, 0);
}

// ---------------------------------------------------------------------------
// fp32 -> f16 conversion pass, load-balanced: grid (512, 4).
// ---------------------------------------------------------------------------
__global__ __launch_bounds__(256) void cvt_pass(
    const float* __restrict__ s0, const float* __restrict__ s1, const float* __restrict__ s2,
    const float* __restrict__ s3, const float* __restrict__ s4, const float* __restrict__ s5,
    const float* __restrict__ s6,
    f16* __restrict__ d0, f16* __restrict__ d1, f16* __restrict__ d2,
    f16* __restrict__ d3, f16* __restrict__ d4, f16* __restrict__ d5, f16* __restrict__ d6)
{
    const int y = blockIdx.y;
    if (y < 3) {
        const float* s = (y == 0) ? s0 : (y == 1) ? s1 : s2;
        f16* d = (y == 0) ? d0 : (y == 1) ? d1 : d2;
        const int n4 = (MM * DD) / 4;
        for (int i = blockIdx.x * 256 + threadIdx.x; i < n4; i += 512 * 256) {
            f32x4 v = ((const f32x4*)s)[i];
            f16x4 h = { (f16)v.x, (f16)v.y, (f16)v.z, (f16)v.w };
            ((f16x4*)d)[i] = h;
        }
    } else {
        const int n4 = (DD * DD) / 4;   // 2^18 per weight
        for (int i = blockIdx.x * 256 + threadIdx.x; i < 4 * n4; i += 512 * 256) {
            int tsel = i >> 18;
            int off = i & (n4 - 1);
            const float* s = (tsel == 0) ? s3 : (tsel == 1) ? s4 : (tsel == 2) ? s5 : s6;
            f16* d = (tsel == 0) ? d3 : (tsel == 1) ? d4 : (tsel == 2) ? d5 : d6;
            f32x4 v = ((const f32x4*)s)[off];
            f16x4 h = { (f16)v.x, (f16)v.y, (f16)v.z, (f16)v.w };
            ((f16x4*)d)[off] = h;
        }
    }
}

// ---------------------------------------------------------------------------
// QKV projection GEMM (pure f16, global_load_lds, 2-phase dbuf counted pipeline)
// ---------------------------------------------------------------------------
__global__ __launch_bounds__(256) void qkv_gemm(
    const f16* __restrict__ Qf, const f16* __restrict__ Kf, const f16* __restrict__ Vf,
    const f16* __restrict__ Wqf, const float* __restrict__ bq,
    const f16* __restrict__ Wkf, const float* __restrict__ bk,
    const f16* __restrict__ Wvf, const float* __restrict__ bv,
    f16* __restrict__ qh, f16* __restrict__ kh, f16* __restrict__ vTh)
{
    const int type = blockIdx.z;
    const f16* X = (type == 0) ? Qf : (type == 1) ? Kf : Vf;
    const f16* W = (type == 0) ? Wqf : (type == 1) ? Wkf : Wvf;
    const float* bias = (type == 0) ? bq : (type == 1) ? bk : bv;
    const int m0 = blockIdx.y * 128, n0 = blockIdx.x * 128;

    __shared__ f16 smem[4][128 * 64];   // a dbuf = smem[0..1], b dbuf = smem[2..3]

    const int t = threadIdx.x;
    const int l = t & 63, w = t >> 6;
    const int c = l & 15, g = l >> 4;
    const int wr = (w >> 1) * 64, wc = (w & 1) * 64;

    f32x4 acc[4][4] = {};

    #define QKV_STAGE(kt, buf) { \
        _Pragma("unroll") \
        for (int p = 0; p < 4; p++) { \
            int idx = w * 4 + p; \
            int gci = idx * 64 + l; \
            int row = gci >> 3, slot = gci & 7; \
            int ss = slot ^ (row & 7); \
            gl_lds16(X + (size_t)(m0 + row) * DD + (kt) * 64 + ss * 8, smem[buf] + idx * 512); \
            gl_lds16(W + (size_t)(n0 + row) * DD + (kt) * 64 + ss * 8, smem[2 + (buf)] + idx * 512); \
        } }

    QKV_STAGE(0, 0);
    for (int k0 = 0; k0 < 16; k0++) {
        asm volatile("s_waitcnt vmcnt(0)");
        __builtin_amdgcn_s_barrier();
        __builtin_amdgcn_sched_barrier(0);
        if (k0 + 1 < 16) QKV_STAGE(k0 + 1, (k0 + 1) & 1);
        const f16* al = smem[k0 & 1];
        const f16* bl = smem[2 + (k0 & 1)];
        #pragma unroll
        for (int kk = 0; kk < 2; kk++) {
            f16x8 af[4], bf[4];
            #pragma unroll
            for (int mi = 0; mi < 4; mi++) {
                int row = wr + mi * 16 + c;
                af[mi] = *(const f16x8*)((const char*)al + swz128(row, kk * 64 + g * 16));
            }
            #pragma unroll
            for (int ni = 0; ni < 4; ni++) {
                int row = wc + ni * 16 + c;
                bf[ni] = *(const f16x8*)((const char*)bl + swz128(row, kk * 64 + g * 16));
            }
            __builtin_amdgcn_s_setprio(1);
            #pragma unroll
            for (int mi = 0; mi < 4; mi++)
                #pragma unroll
                for (int ni = 0; ni < 4; ni++)
                    acc[mi][ni] = __builtin_amdgcn_mfma_f32_16x16x32_f16(af[mi], bf[ni], acc[mi][ni], 0, 0, 0);
            __builtin_amdgcn_s_setprio(0);
        }
    }
    #undef QKV_STAGE

    const int b = m0 >> 11;
    const int mloc = m0 & (SS - 1);

    if (type == 2) {
        // transpose epilogue: acc -> LDS [n][m] f16 (swizzled) -> coalesced vTh
        __syncthreads();
        f16* tb = smem[0];   // 32 KB
        #pragma unroll
        for (int mi = 0; mi < 4; mi++) {
            #pragma unroll
            for (int ni = 0; ni < 4; ni++) {
                int nl = wc + ni * 16 + c;
                int mb = (wr + mi * 16 + g * 4) * 2;   // byte col in 256B row
                f16x4 hv;
                #pragma unroll
                for (int r = 0; r < 4; r++)
                    hv[r] = (f16)(acc[mi][ni][r] + bias[n0 + nl]);
                *(f16x4*)((char*)tb + nl * 256 + (mb ^ ((nl & 7) << 4))) = hv;
            }
        }
        __syncthreads();
        #pragma unroll
        for (int i = 0; i < 8; i++) {
            int o = w * 8192 + i * 1024 + l * 16;   // byte offset into 32 KB
            int nl = o >> 8;
            int inb = o & 255;
            f16x8 v = *(const f16x8*)((char*)tb + nl * 256 + (inb ^ ((nl & 7) << 4)));
            int ng = n0 + nl, h_ = ng >> 6, dk = ng & 63;
            int s = mloc + inb / 2;
            *(f16x8*)(vTh + ((size_t)((b * HH + h_) * DKK + dk)) * SS + s) = v;
        }
    } else {
        // row-major epilogue via LDS: acc -> LDS [m][n] f16 (swizzled) -> dense q/k
        __syncthreads();
        f16* tb = smem[0];   // 32 KB: 128 rows x 256B
        #pragma unroll
        for (int mi = 0; mi < 4; mi++) {
            #pragma unroll
            for (int ni = 0; ni < 4; ni++) {
                int nl = wc + ni * 16 + c;
                float bv_ = bias[n0 + nl];
                #pragma unroll
                for (int r = 0; r < 4; r++) {
                    int ml = wr + mi * 16 + g * 4 + r;
                    *(f16*)((char*)tb + ml * 256 + ((nl * 2) ^ ((ml & 7) << 4))) =
                        (f16)(acc[mi][ni][r] + bv_);
                }
            }
        }
        __syncthreads();
        f16* dst = (type == 0) ? qh : kh;
        #pragma unroll
        for (int i = 0; i < 8; i++) {
            int o = w * 8192 + i * 1024 + l * 16;
            int row = o >> 8, inb = o & 255;
            f16x8 v = *(const f16x8*)((char*)tb + row * 256 + (inb ^ ((row & 7) << 4)));
            int nl = inb / 2;
            int ng = n0 + nl, h_ = ng >> 6, dk = ng & 63;
            *(f16x8*)(dst + ((size_t)((b * HH + h_) * SS + mloc + row)) * DKK + dk) = v;
        }
    }
}

// ---------------------------------------------------------------------------
// Swapped-operand flash attention, BM=128: 32 q-rows per wave -> each K/V LDS
// fragment feeds 2 MFMAs (halves LDS instruction pressure, barriers, K/V loads).
// Skewed pipeline + counted-vmcnt barriers. P staged f16 in LDS for dense stores.
// ---------------------------------------------------------------------------
__global__ __launch_bounds__(256) void attn_kernel(
    const f16* __restrict__ qh, const f16* __restrict__ kh, const f16* __restrict__ vTh,
    float* __restrict__ attn_out, f16* __restrict__ ctx)
{
    const int bid = blockIdx.x;                  // 512 blocks
    const int swz = (bid & 7) * 64 + (bid >> 3);
    const int bh = swz >> 4;
    const int qb2 = 15 - (swz & 15);             // heavy blocks first (LPT)
    const int qbase = qb2 * 128;
    const int dj = 2 * qb2;                      // first masked tile index
    const int nj = dj + 2;                       // tiles 0..nj-1
    const int t = threadIdx.x, l = t & 63, w = t >> 6;
    const int c = l & 15, g = l >> 4;

    __shared__ f16 kb3[3][64 * 64];   // 24 KB
    __shared__ f16 vb3[3][64 * 64];   // 24 KB (sweep2: first 16 KB = f16 P tile)

    const float CSC = 0.125f * 1.44269504f;  // /sqrt(64) * log2(e)

    const f16* kbase = kh + (size_t)bh * SS * DKK;
    const f16* vbase = vTh + (size_t)bh * DKK * SS;
    float* aout = attn_out + (size_t)bh * SS * SS;

    // Q B-fragments for both 16-row sub-groups (rows w*32+sub*16+c)
    f16x8 bqf[2][2];
    {
        const f16* q0 = qh + (size_t)bh * SS * DKK + (size_t)(qbase + w * 32 + c) * DKK;
        bqf[0][0] = *(const f16x8*)(q0 + g * 8);
        bqf[0][1] = *(const f16x8*)(q0 + 32 + g * 8);
        const f16* q1 = q0 + 16 * DKK;
        bqf[1][0] = *(const f16x8*)(q1 + g * 8);
        bqf[1][1] = *(const f16x8*)(q1 + 32 + g * 8);
    }

    #define STAGE_K(jt, buf) { \
        const f16* ksrc_ = kbase + (size_t)(jt) * 64 * DKK; \
        _Pragma("unroll") \
        for (int p = 0; p < 2; p++) { \
            int idx = w * 2 + p; \
            int gci = idx * 64 + l; \
            int row = gci >> 3, slot = gci & 7; \
            int ss_ = slot ^ (row & 7); \
            gl_lds16(ksrc_ + row * DKK + ss_ * 8, kb3[buf] + idx * 512); \
        } }
    #define STAGE_V(jt, buf) { \
        const f16* vsrc_ = vbase + (size_t)(jt) * 64; \
        _Pragma("unroll") \
        for (int p = 0; p < 2; p++) { \
            int idx = w * 2 + p; \
            int gci = idx * 64 + l; \
            int row = gci >> 3, slot = gci & 7; \
            int ss_ = slot ^ (row & 7); \
            gl_lds16(vsrc_ + (size_t)row * SS + ss_ * 8, vb3[buf] + idx * 512); \
        } }

    // QK^T: A-frag (K rows) read ONCE, feeds both sub-group MFMAs
    #define QKT2(dstf, srcb) { \
        __builtin_amdgcn_s_setprio(1); \
        _Pragma("unroll") \
        for (int dw = 0; dw < 2; dw++) { \
            _Pragma("unroll") \
            for (int ni = 0; ni < 4; ni++) { \
                f16x8 ak = *(const f16x8*)((const char*)(srcb) + swz128(ni * 16 + c, dw * 64 + g * 16)); \
                dstf[0][ni] = __builtin_amdgcn_mfma_f32_16x16x32_f16(ak, bqf[0][dw], dstf[0][ni], 0, 0, 0); \
                dstf[1][ni] = __builtin_amdgcn_mfma_f32_16x16x32_f16(ak, bqf[1][dw], dstf[1][ni], 0, 0, 0); \
            } \
        } \
        __builtin_amdgcn_s_setprio(0); }

    // finish tile: exp (optionally masked with k-offset koff) + PV accumulate.
    // V A-frag read once, feeds both sub-groups.
    #define FINISH(pvv, MASKED, koff) { \
        f16x4 bfr[2][4]; \
        _Pragma("unroll") \
        for (int sub = 0; sub < 2; sub++) { \
            int rl = w * 32 + sub * 16 + c; \
            _Pragma("unroll") \
            for (int ni = 0; ni < 4; ni++) { \
                int kkb = ni * 16 + 4 * g + (koff); \
                float e0 = exp2f(sprev[sub][ni][0] * CSC); if ((MASKED) && kkb + 0 > rl) e0 = 0.f; \
                float e1 = exp2f(sprev[sub][ni][1] * CSC); if ((MASKED) && kkb + 1 > rl) e1 = 0.f; \
                float e2 = exp2f(sprev[sub][ni][2] * CSC); if ((MASKED) && kkb + 2 > rl) e2 = 0.f; \
                float e3 = exp2f(sprev[sub][ni][3] * CSC); if ((MASKED) && kkb + 3 > rl) e3 = 0.f; \
                lrow[sub] += e0 + e1 + e2 + e3; \
                bfr[sub][ni] = f16x4{ (f16)e0, (f16)e1, (f16)e2, (f16)e3 }; \
            } \
        } \
        __builtin_amdgcn_s_setprio(1); \
        _Pragma("unroll") \
        for (int ni2 = 0; ni2 < 4; ni2++) { \
            _Pragma("unroll") \
            for (int nk = 0; nk < 4; nk++) { \
                f16x4 av = *(const f16x4*)((const char*)(pvv) + swz128(ni2 * 16 + c, nk * 32 + g * 8)); \
                cacc[0][ni2] = __builtin_amdgcn_mfma_f32_16x16x16f16(av, bfr[0][nk], cacc[0][ni2], 0, 0, 0); \
                cacc[1][ni2] = __builtin_amdgcn_mfma_f32_16x16x16f16(av, bfr[1][nk], cacc[1][ni2], 0, 0, 0); \
            } \
        } \
        __builtin_amdgcn_s_setprio(0); }

    // sweep-2: normalized P -> f16 LDS tile (128 rows x 128B, swizzled)
    #define PCOMP(MASKED, koff) { \
        char* pl_ = (char*)vb3; \
        _Pragma("unroll") \
        for (int sub = 0; sub < 2; sub++) { \
            int rl = w * 32 + sub * 16 + c; \
            _Pragma("unroll") \
            for (int ni = 0; ni < 4; ni++) { \
                int kkb = ni * 16 + 4 * g + (koff); \
                float p0 = exp2f(fmaf(sprev[sub][ni][0], CSC, nls[sub])); if ((MASKED) && kkb + 0 > rl) p0 = 0.f; \
                float p1 = exp2f(fmaf(sprev[sub][ni][1], CSC, nls[sub])); if ((MASKED) && kkb + 1 > rl) p1 = 0.f; \
                float p2 = exp2f(fmaf(sprev[sub][ni][2], CSC, nls[sub])); if ((MASKED) && kkb + 2 > rl) p2 = 0.f; \
                float p3 = exp2f(fmaf(sprev[sub][ni][3], CSC, nls[sub])); if ((MASKED) && kkb + 3 > rl) p3 = 0.f; \
                f16x4 hv = { (f16)p0, (f16)p1, (f16)p2, (f16)p3 }; \
                *(f16x4*)(pl_ + rl * 128 + ((ni * 32 + g * 8) ^ ((rl & 7) << 4))) = hv; \
            } \
        } }

    // wave-local: read back own 32 rows, cvt to f32, dense NT store
    #define PSTORE(jt) { \
        const char* pl_ = (const char*)vb3; \
        _Pragma("unroll") \
        for (int i = 0; i < 8; i++) { \
            int row_ = w * 32 + i * 4 + g; \
            f16x4 hv = *(const f16x4*)(pl_ + row_ * 128 + ((c * 8) ^ ((row_ & 7) << 4))); \
            f32x4 v_ = { (float)hv[0], (float)hv[1], (float)hv[2], (float)hv[3] }; \
            __builtin_nontemporal_store(v_, (f32x4*)(aout + (size_t)(qbase + row_) * SS + (jt) * 64 + c * 4)); \
        } }

    #define CBAR(n) { asm volatile("s_waitcnt vmcnt(" #n ")"); \
                      __builtin_amdgcn_s_barrier(); \
                      __builtin_amdgcn_sched_barrier(0); }

    // ==== sweep 1: row sums + unnormalized ctx (PV), skewed, counted vmcnt ====
    STAGE_K(0, 0);
    STAGE_K(1, 1);
    STAGE_V(0, 0);
    CBAR(0);

    float lrow[2] = { 0.f, 0.f };
    f32x4 cacc[2][4] = {};
    f32x4 sprev[2][4];

    for (int j = 0; j < nj; j++) {
        if (j + 2 < nj) STAGE_K(j + 2, (j + 2) % 3);
        if (j + 1 < nj) STAGE_V(j + 1, (j + 1) % 3);

        f32x4 scur[2][4] = {};
        QKT2(scur, kb3[j % 3]);

        if (j > 0) {
            const f16* pvv = vb3[(j - 1) % 3];
            if (j - 1 < dj) { FINISH(pvv, 0, 0); }
            else            { FINISH(pvv, 1, 0); }   // tile dj: diagonal for lower half
        }

        if (j + 3 <= nj)      CBAR(4)
        else if (j + 2 == nj) CBAR(2)
        else                  CBAR(0);

        #pragma unroll
        for (int sub = 0; sub < 2; sub++)
            #pragma unroll
            for (int x = 0; x < 4; x++) sprev[sub][x] = scur[sub][x];
    }

    // issue sweep-2's K0/K1 early; latency hides under the epilogue VALU
    STAGE_K(0, 0);
    STAGE_K(1, 1);

    // epilogue: finish tile nj-1 (masked, koff=64)
    {
        const f16* pvv = vb3[(nj - 1) % 3];
        FINISH(pvv, 1, 64);
    }

    // row-sum reduce across the 4 lane groups (same q)
    float nls[2];
    #pragma unroll
    for (int sub = 0; sub < 2; sub++) {
        float s = lrow[sub];
        s += __shfl_xor(s, 16);
        s += __shfl_xor(s, 32);
        lrow[sub] = s;
        nls[sub] = -__log2f(s);
    }

    // store ctx (normalized)
    {
        int b = bh >> 4, h_ = bh & 15;
        #pragma unroll
        for (int sub = 0; sub < 2; sub++) {
            float rinv = 1.f / lrow[sub];
            int rl = w * 32 + sub * 16 + c;
            f16* cbase = ctx + (size_t)(b * SS + qbase + rl) * DD + h_ * 64;
            #pragma unroll
            for (int ni2 = 0; ni2 < 4; ni2++) {
                f16x4 hv = { (f16)(cacc[sub][ni2][0] * rinv), (f16)(cacc[sub][ni2][1] * rinv),
                             (f16)(cacc[sub][ni2][2] * rinv), (f16)(cacc[sub][ni2][3] * rinv) };
                *(f16x4*)(cbase + ni2 * 16 + 4 * g) = hv;
            }
        }
    }

    CBAR(0);   // K0/K1 ready; all sweep-1 vb3 reads done before P-tile reuse

    // ==== sweep 2: normalized prob store stream, skewed ====
    {
        f32x4 sprev2[2][4];
        for (int j = 0; j < nj; j++) {
            if (j + 2 < nj) STAGE_K(j + 2, (j + 2) % 3);

            f32x4 scur[2][4] = {};
            QKT2(scur, kb3[j % 3]);

            if (j > 0) {
                #pragma unroll
                for (int sub = 0; sub < 2; sub++)
                    #pragma unroll
                    for (int x = 0; x < 4; x++) sprev[sub][x] = sprev2[sub][x];
                if (j - 1 < dj) { PCOMP(0, 0); }
                else            { PCOMP(1, 0); }
                PSTORE(j - 1);
            }

            if (j == 0 && j + 2 < nj)  CBAR(2)     // 2 K-loads only
            else if (j + 2 < nj)       CBAR(10)    // 2 K-loads + 8 NT stores
            else if (j > 0)            CBAR(8)     // 8 NT stores only
            else                       CBAR(0);

            #pragma unroll
            for (int sub = 0; sub < 2; sub++)
                #pragma unroll
                for (int x = 0; x < 4; x++) sprev2[sub][x] = scur[sub][x];
        }

        // epilogue: tile nj-1 (masked, koff=64)
        #pragma unroll
        for (int sub = 0; sub < 2; sub++)
            #pragma unroll
            for (int x = 0; x < 4; x++) sprev[sub][x] = sprev2[sub][x];
        PCOMP(1, 64);
        PSTORE(nj - 1);
    }

    // zero this row-strip's strictly-upper blocks (dense NT stores)
    {
        f32x4 z = { 0.f, 0.f, 0.f, 0.f };
        for (int jb = nj; jb < 32; jb++) {
            #pragma unroll
            for (int i = 0; i < 8; i++) {
                int c2 = t + 256 * i;
                int row = c2 >> 4, cg = c2 & 15;
                __builtin_nontemporal_store(z, (f32x4*)(aout + (size_t)(qbase + row) * SS + jb * 64 + cg * 4));
            }
        }
    }
    #undef STAGE_K
    #undef STAGE_V
    #undef QKT2
    #undef FINISH
    #undef PCOMP
    #undef PSTORE
    #undef CBAR
}

// ---------------------------------------------------------------------------
// Output projection (pure f16, 2-phase dbuf counted pipeline): ctx.Wo^T+bo+resid
// Epilogue via 64KB LDS transpose -> dense loads; f16 output (LN input).
// ---------------------------------------------------------------------------
__global__ __launch_bounds__(256) void oproj_gemm(
    const f16* __restrict__ A, const f16* __restrict__ Wof, const float* __restrict__ bo,
    const float* __restrict__ resid, f16* __restrict__ out)
{
    const int m0 = blockIdx.y * 128, n0 = blockIdx.x * 128;
    __shared__ f16 smem[4][128 * 64];
    const int t = threadIdx.x;
    const int l = t & 63, w = t >> 6;
    const int c = l & 15, g = l >> 4;
    const int wr = (w >> 1) * 64, wc = (w & 1) * 64;

    f32x4 acc[4][4] = {};

    #define OP_STAGE(kt, buf) { \
        _Pragma("unroll") \
        for (int p = 0; p < 4; p++) { \
            int idx = w * 4 + p; \
            int gci = idx * 64 + l; \
            int row = gci >> 3, slot = gci & 7; \
            int ss = slot ^ (row & 7); \
            gl_lds16(A + (size_t)(m0 + row) * DD + (kt) * 64 + ss * 8, smem[buf] + idx * 512); \
            gl_lds16(Wof + (size_t)(n0 + row) * DD + (kt) * 64 + ss * 8, smem[2 + (buf)] + idx * 512); \
        } }

    OP_STAGE(0, 0);
    for (int k0 = 0; k0 < 16; k0++) {
        asm volatile("s_waitcnt vmcnt(0)");
        __builtin_amdgcn_s_barrier();
        __builtin_amdgcn_sched_barrier(0);
        if (k0 + 1 < 16) OP_STAGE(k0 + 1, (k0 + 1) & 1);
        const f16* al = smem[k0 & 1];
        const f16* bl = smem[2 + (k0 & 1)];
        #pragma unroll
        for (int kk = 0; kk < 2; kk++) {
            f16x8 af[4], bf[4];
            #pragma unroll
            for (int mi = 0; mi < 4; mi++) {
                int row = wr + mi * 16 + c;
                af[mi] = *(const f16x8*)((const char*)al + swz128(row, kk * 64 + g * 16));
            }
            #pragma unroll
            for (int ni = 0; ni < 4; ni++) {
                int row = wc + ni * 16 + c;
                bf[ni] = *(const f16x8*)((const char*)bl + swz128(row, kk * 64 + g * 16));
            }
            __builtin_amdgcn_s_setprio(1);
            #pragma unroll
            for (int mi = 0; mi < 4; mi++)
                #pragma unroll
                for (int ni = 0; ni < 4; ni++)
                    acc[mi][ni] = __builtin_amdgcn_mfma_f32_16x16x32_f16(af[mi], bf[ni], acc[mi][ni], 0, 0, 0);
            __builtin_amdgcn_s_setprio(0);
        }
    }
    #undef OP_STAGE

    __syncthreads();
    float* tb = (float*)smem;
    #pragma unroll
    for (int mi = 0; mi < 4; mi++) {
        #pragma unroll
        for (int ni = 0; ni < 4; ni++) {
            int nl = wc + ni * 16 + c;
            #pragma unroll
            for (int r = 0; r < 4; r++) {
                int ml = wr + mi * 16 + g * 4 + r;
                *(float*)((char*)tb + ml * 512 + ((nl * 4) ^ ((ml & 7) << 4))) = acc[mi][ni][r];
            }
        }
    }
    __syncthreads();
    #pragma unroll
    for (int i = 0; i < 16; i++) {
        int o = w * 16384 + i * 1024 + l * 16;
        int row = o >> 9, inb = o & 511;
        f32x4 v = *(const f32x4*)((char*)tb + row * 512 + (inb ^ ((row & 7) << 4)));
        int nl = inb / 4;
        int n = n0 + nl, m = m0 + row;
        f32x4 bo4 = *(const f32x4*)(bo + n);
        f32x4 rs4 = *(const f32x4*)(resid + (size_t)m * DD + n);
        v = v + bo4 + rs4;
        f16x4 hv = { (f16)v.x, (f16)v.y, (f16)v.z, (f16)v.w };
        *(f16x4*)(out + (size_t)m * DD + n) = hv;
    }
}

// ---------------------------------------------------------------------------
// Row LayerNorm: one block per row of 1024; f16 input, f32 output
// ---------------------------------------------------------------------------
__global__ __launch_bounds__(256) void ln_kernel(
    const f16* __restrict__ x, const float* __restrict__ gamma,
    const float* __restrict__ beta, float* __restrict__ out)
{
    int row = blockIdx.x;
    int t = threadIdx.x;
    f16x4 xv = ((const f16x4*)(x + (size_t)row * DD))[t];
    float4 v = { (float)xv[0], (float)xv[1], (float)xv[2], (float)xv[3] };
    float s = v.x + v.y + v.z + v.w;
    __shared__ float red[4];
    #pragma unroll
    for (int o = 32; o; o >>= 1) s += __shfl_down(s, o, 64);
    if ((t & 63) == 0) red[t >> 6] = s;
    __syncthreads();
    float mean = (red[0] + red[1] + red[2] + red[3]) * (1.f / DD);
    __syncthreads();
    float4 d;
    d.x = v.x - mean; d.y = v.y - mean; d.z = v.z - mean; d.w = v.w - mean;
    float q = d.x * d.x + d.y * d.y + d.z * d.z + d.w * d.w;
    #pragma unroll
    for (int o = 32; o; o >>= 1) q += __shfl_down(q, o, 64);
    if ((t & 63) == 0) red[t >> 6] = q;
    __syncthreads();
    float var = (red[0] + red[1] + red[2] + red[3]) * (1.f / DD);
    float rstd = rsqrtf(var + EPSF);
    float4 g = ((const float4*)gamma)[t];
    float4 bt = ((const float4*)beta)[t];
    float4 o4;
    o4.x = d.x * rstd * g.x + bt.x;
    o4.y = d.y * rstd * g.y + bt.y;
    o4.z = d.z * rstd * g.z + bt.z;
    o4.w = d.w * rstd * g.w + bt.w;
    ((float4*)(out + (size_t)row * DD))[t] = o4;
}

extern "C" void kernel_launch(void* const* d_in, const int* in_sizes, int n_in,
                              void* d_out, int out_size, void* d_ws, size_t ws_size,
                              hipStream_t stream)
{
    const float* Q     = (const float*)d_in[0];
    const float* K     = (const float*)d_in[1];
    const float* V     = (const float*)d_in[2];
    const float* Wq    = (const float*)d_in[4];
    const float* bq    = (const float*)d_in[5];
    const float* Wk    = (const float*)d_in[6];
    const float* bk    = (const float*)d_in[7];
    const float* Wv    = (const float*)d_in[8];
    const float* bv    = (const float*)d_in[9];
    const float* Wo    = (const float*)d_in[10];
    const float* bo    = (const float*)d_in[11];
    const float* gamma = (const float*)d_in[12];
    const float* beta  = (const float*)d_in[13];

    float* out_ln   = (float*)d_out;
    float* attn_out = (float*)d_out + (size_t)BB * SS * DD;

    // transient f16 scratch inside d_out regions that are overwritten later
    f16* Qf  = (f16*)attn_out;
    f16* Kf  = Qf + (size_t)MM * DD;
    f16* Vf  = Kf + (size_t)MM * DD;
    f16* Wqf = (f16*)out_ln;
    f16* Wkf = Wqf + (size_t)DD * DD;
    f16* Wvf = Wkf + (size_t)DD * DD;
    f16* Wof = Wvf + (size_t)DD * DD;

    char* ws = (char*)d_ws;
    f16*   qh    = (f16*)(ws);                        // 8 MB
    f16*   kh    = (f16*)(ws + ((size_t)8  << 20));   // 8 MB
    f16*   vTh   = (f16*)(ws + ((size_t)16 << 20));   // 8 MB
    f16*   ctx   = (f16*)(ws + ((size_t)24 << 20));   // 8 MB
    f16*   oproj = (f16*)(ws + ((size_t)32 << 20));   // 8 MB (f16)

    cvt_pass<<<dim3(512, 4), 256, 0, stream>>>(Q, K, V, Wq, Wk, Wv, Wo,
                                               Qf, Kf, Vf, Wqf, Wkf, Wvf, Wof);
    qkv_gemm<<<dim3(8, 32, 3), 256, 0, stream>>>(Qf, Kf, Vf, Wqf, bq, Wkf, bk, Wvf, bv, qh, kh, vTh);
    attn_kernel<<<dim3(512), 256, 0, stream>>>(qh, kh, vTh, attn_out, ctx);
    oproj_gemm<<<dim3(8, 32), 256, 0, stream>>>(ctx, Wof, bo, Q, oproj);
    ln_kernel<<<dim3(MM), 256, 0, stream>>>(oproj, gamma, beta, out_ln);
}

// Round 17
// 206.929 us; speedup vs baseline: 1.1529x; 1.1529x over previous
//
#include <hip/hip_runtime.h>
#include <hip/hip_fp16.h>

#define BB 2
#define SS 2048
#define DD 1024
#define HH 16
#define DKK 64
#define BHH (BB*HH)
#define MM (BB*SS)
#define EPSF 1e-5f

typedef _Float16 f16;
typedef _Float16 f16x4 __attribute__((ext_vector_type(4)));
typedef _Float16 f16x8 __attribute__((ext_vector_type(8)));
typedef float f32x4 __attribute__((ext_vector_type(4)));

// XOR swizzle for 128-byte LDS rows: permutes 16B slots, kills stride-128B bank conflicts
__device__ __forceinline__ int swz128(int row, int byteInRow) {
    return row * 128 + (byteInRow ^ ((row & 7) << 4));
}

// global -> LDS direct (16B per lane). LDS dest is wave-uniform base + lane*16.
__device__ __forceinline__ void gl_lds16(const f16* g, f16* l) {
    __builtin_amdgcn_global_load_lds((const __attribute__((address_space(1))) void*)g,
                                     (__attribute__((address_space(3))) void*)l, 16, 0, 0);
}

// ---------------------------------------------------------------------------
// fp32 -> f16 conversion pass, load-balanced: grid (512, 4).
// y=0..2: Q,K,V (1M f32x4 each). y=3: the 4 weights as one flat range.
// ---------------------------------------------------------------------------
__global__ __launch_bounds__(256) void cvt_pass(
    const float* __restrict__ s0, const float* __restrict__ s1, const float* __restrict__ s2,
    const float* __restrict__ s3, const float* __restrict__ s4, const float* __restrict__ s5,
    const float* __restrict__ s6,
    f16* __restrict__ d0, f16* __restrict__ d1, f16* __restrict__ d2,
    f16* __restrict__ d3, f16* __restrict__ d4, f16* __restrict__ d5, f16* __restrict__ d6)
{
    const int y = blockIdx.y;
    if (y < 3) {
        const float* s = (y == 0) ? s0 : (y == 1) ? s1 : s2;
        f16* d = (y == 0) ? d0 : (y == 1) ? d1 : d2;
        const int n4 = (MM * DD) / 4;
        for (int i = blockIdx.x * 256 + threadIdx.x; i < n4; i += 512 * 256) {
            f32x4 v = ((const f32x4*)s)[i];
            f16x4 h = { (f16)v.x, (f16)v.y, (f16)v.z, (f16)v.w };
            ((f16x4*)d)[i] = h;
        }
    } else {
        const int n4 = (DD * DD) / 4;   // 2^18 per weight
        for (int i = blockIdx.x * 256 + threadIdx.x; i < 4 * n4; i += 512 * 256) {
            int tsel = i >> 18;
            int off = i & (n4 - 1);
            const float* s = (tsel == 0) ? s3 : (tsel == 1) ? s4 : (tsel == 2) ? s5 : s6;
            f16* d = (tsel == 0) ? d3 : (tsel == 1) ? d4 : (tsel == 2) ? d5 : d6;
            f32x4 v = ((const f32x4*)s)[off];
            f16x4 h = { (f16)v.x, (f16)v.y, (f16)v.z, (f16)v.w };
            ((f16x4*)d)[off] = h;
        }
    }
}

// ---------------------------------------------------------------------------
// QKV projection GEMM (pure f16, global_load_lds, 2-phase dbuf counted pipeline)
// q,k stored [BH][S][DK]; v stored transposed [BH][DK][S]. ALL outputs routed
// through LDS-transposed coalesced epilogues (dense 16B/lane stores).
// ---------------------------------------------------------------------------
__global__ __launch_bounds__(256) void qkv_gemm(
    const f16* __restrict__ Qf, const f16* __restrict__ Kf, const f16* __restrict__ Vf,
    const f16* __restrict__ Wqf, const float* __restrict__ bq,
    const f16* __restrict__ Wkf, const float* __restrict__ bk,
    const f16* __restrict__ Wvf, const float* __restrict__ bv,
    f16* __restrict__ qh, f16* __restrict__ kh, f16* __restrict__ vTh)
{
    const int type = blockIdx.z;
    const f16* X = (type == 0) ? Qf : (type == 1) ? Kf : Vf;
    const f16* W = (type == 0) ? Wqf : (type == 1) ? Wkf : Wvf;
    const float* bias = (type == 0) ? bq : (type == 1) ? bk : bv;
    const int m0 = blockIdx.y * 128, n0 = blockIdx.x * 128;

    __shared__ f16 smem[4][128 * 64];   // a dbuf = smem[0..1], b dbuf = smem[2..3]

    const int t = threadIdx.x;
    const int l = t & 63, w = t >> 6;
    const int c = l & 15, g = l >> 4;
    const int wr = (w >> 1) * 64, wc = (w & 1) * 64;

    f32x4 acc[4][4] = {};

    #define QKV_STAGE(kt, buf) { \
        _Pragma("unroll") \
        for (int p = 0; p < 4; p++) { \
            int idx = w * 4 + p; \
            int gci = idx * 64 + l; \
            int row = gci >> 3, slot = gci & 7; \
            int ss = slot ^ (row & 7); \
            gl_lds16(X + (size_t)(m0 + row) * DD + (kt) * 64 + ss * 8, smem[buf] + idx * 512); \
            gl_lds16(W + (size_t)(n0 + row) * DD + (kt) * 64 + ss * 8, smem[2 + (buf)] + idx * 512); \
        } }

    QKV_STAGE(0, 0);
    for (int k0 = 0; k0 < 16; k0++) {
        asm volatile("s_waitcnt vmcnt(0)");
        __builtin_amdgcn_s_barrier();
        __builtin_amdgcn_sched_barrier(0);
        if (k0 + 1 < 16) QKV_STAGE(k0 + 1, (k0 + 1) & 1);
        const f16* al = smem[k0 & 1];
        const f16* bl = smem[2 + (k0 & 1)];
        #pragma unroll
        for (int kk = 0; kk < 2; kk++) {
            f16x8 af[4], bf[4];
            #pragma unroll
            for (int mi = 0; mi < 4; mi++) {
                int row = wr + mi * 16 + c;
                af[mi] = *(const f16x8*)((const char*)al + swz128(row, kk * 64 + g * 16));
            }
            #pragma unroll
            for (int ni = 0; ni < 4; ni++) {
                int row = wc + ni * 16 + c;
                bf[ni] = *(const f16x8*)((const char*)bl + swz128(row, kk * 64 + g * 16));
            }
            __builtin_amdgcn_s_setprio(1);
            #pragma unroll
            for (int mi = 0; mi < 4; mi++)
                #pragma unroll
                for (int ni = 0; ni < 4; ni++)
                    acc[mi][ni] = __builtin_amdgcn_mfma_f32_16x16x32_f16(af[mi], bf[ni], acc[mi][ni], 0, 0, 0);
            __builtin_amdgcn_s_setprio(0);
        }
    }
    #undef QKV_STAGE

    const int b = m0 >> 11;
    const int mloc = m0 & (SS - 1);

    if (type == 2) {
        // transpose epilogue: acc -> LDS [n][m] f16 (swizzled) -> coalesced vTh
        __syncthreads();
        f16* tb = smem[0];   // 32 KB
        #pragma unroll
        for (int mi = 0; mi < 4; mi++) {
            #pragma unroll
            for (int ni = 0; ni < 4; ni++) {
                int nl = wc + ni * 16 + c;
                int mb = (wr + mi * 16 + g * 4) * 2;   // byte col in 256B row
                f16x4 hv;
                #pragma unroll
                for (int r = 0; r < 4; r++)
                    hv[r] = (f16)(acc[mi][ni][r] + bias[n0 + nl]);
                *(f16x4*)((char*)tb + nl * 256 + (mb ^ ((nl & 7) << 4))) = hv;
            }
        }
        __syncthreads();
        #pragma unroll
        for (int i = 0; i < 8; i++) {
            int o = w * 8192 + i * 1024 + l * 16;   // byte offset into 32 KB
            int nl = o >> 8;
            int inb = o & 255;
            f16x8 v = *(const f16x8*)((char*)tb + nl * 256 + (inb ^ ((nl & 7) << 4)));
            int ng = n0 + nl, h_ = ng >> 6, dk = ng & 63;
            int s = mloc + inb / 2;
            *(f16x8*)(vTh + ((size_t)((b * HH + h_) * DKK + dk)) * SS + s) = v;
        }
    } else {
        // row-major epilogue via LDS: acc -> LDS [m][n] f16 (swizzled) -> dense q/k
        __syncthreads();
        f16* tb = smem[0];   // 32 KB: 128 rows x 256B
        #pragma unroll
        for (int mi = 0; mi < 4; mi++) {
            #pragma unroll
            for (int ni = 0; ni < 4; ni++) {
                int nl = wc + ni * 16 + c;
                float bv_ = bias[n0 + nl];
                #pragma unroll
                for (int r = 0; r < 4; r++) {
                    int ml = wr + mi * 16 + g * 4 + r;
                    *(f16*)((char*)tb + ml * 256 + ((nl * 2) ^ ((ml & 7) << 4))) =
                        (f16)(acc[mi][ni][r] + bv_);
                }
            }
        }
        __syncthreads();
        f16* dst = (type == 0) ? qh : kh;
        #pragma unroll
        for (int i = 0; i < 8; i++) {
            int o = w * 8192 + i * 1024 + l * 16;
            int row = o >> 8, inb = o & 255;
            f16x8 v = *(const f16x8*)((char*)tb + row * 256 + (inb ^ ((row & 7) << 4)));
            int nl = inb / 2;
            int ng = n0 + nl, h_ = ng >> 6, dk = ng & 63;
            *(f16x8*)(dst + ((size_t)((b * HH + h_) * SS + mloc + row)) * DKK + dk) = v;
        }
    }
}

// ---------------------------------------------------------------------------
// Swapped-operand flash attention, skewed pipeline + counted-vmcnt barriers.
// Heavy blocks first (descending qb = longest-job-first).
// ---------------------------------------------------------------------------
__global__ __launch_bounds__(256) void attn_kernel(
    const f16* __restrict__ qh, const f16* __restrict__ kh, const f16* __restrict__ vTh,
    float* __restrict__ attn_out, f16* __restrict__ ctx)
{
    const int bid = blockIdx.x;                  // 1024 blocks
    const int swz = (bid & 7) * 128 + (bid >> 3);
    const int bh = swz >> 5;
    const int qb = 31 - (swz & 31);              // heavy blocks first within XCD chunk
    const int qbase = qb * 64;
    const int t = threadIdx.x, l = t & 63, w = t >> 6;
    const int c = l & 15, g = l >> 4;

    __shared__ f16 kb3[3][64 * 64];   // 24 KB
    __shared__ f16 vb3[3][64 * 64];   // 24 KB (sweep2: first 16 KB = pl)

    const float CSC = 0.125f * 1.44269504f;  // /sqrt(64) * log2(e)
    const int nj = qb + 1;
    const int qloc = w * 16 + c;
    const int qglob = qbase + qloc;

    const f16* kbase = kh + (size_t)bh * SS * DKK;
    const f16* vbase = vTh + (size_t)bh * DKK * SS;
    float* aout = attn_out + (size_t)bh * SS * SS;

    // Q fragments direct from global (one-time, L2)
    const f16* qsrc = qh + (size_t)bh * SS * DKK + (size_t)qglob * DKK;
    f16x8 bq[2];
    bq[0] = *(const f16x8*)(qsrc + g * 8);
    bq[1] = *(const f16x8*)(qsrc + 32 + g * 8);

    #define STAGE_K(jt, buf) { \
        const f16* ksrc_ = kbase + (size_t)(jt) * 64 * DKK; \
        _Pragma("unroll") \
        for (int p = 0; p < 2; p++) { \
            int idx = w * 2 + p; \
            int gci = idx * 64 + l; \
            int row = gci >> 3, slot = gci & 7; \
            int ss_ = slot ^ (row & 7); \
            gl_lds16(ksrc_ + row * DKK + ss_ * 8, kb3[buf] + idx * 512); \
        } }
    #define STAGE_V(jt, buf) { \
        const f16* vsrc_ = vbase + (size_t)(jt) * 64; \
        _Pragma("unroll") \
        for (int p = 0; p < 2; p++) { \
            int idx = w * 2 + p; \
            int gci = idx * 64 + l; \
            int row = gci >> 3, slot = gci & 7; \
            int ss_ = slot ^ (row & 7); \
            gl_lds16(vsrc_ + (size_t)row * SS + ss_ * 8, vb3[buf] + idx * 512); \
        } }

    #define QKT(dstf, srcb) { \
        __builtin_amdgcn_s_setprio(1); \
        _Pragma("unroll") \
        for (int dw = 0; dw < 2; dw++) { \
            _Pragma("unroll") \
            for (int ni = 0; ni < 4; ni++) { \
                f16x8 ak = *(const f16x8*)((const char*)(srcb) + swz128(ni * 16 + c, dw * 64 + g * 16)); \
                dstf[ni] = __builtin_amdgcn_mfma_f32_16x16x32_f16(ak, bq[dw], dstf[ni], 0, 0, 0); \
            } \
        } \
        __builtin_amdgcn_s_setprio(0); }

    // wave-local LDS transpose store of one 64x64 P-tile (rows w*16..w*16+15)
    #define PSTORE(jt) { \
        float* pl_ = (float*)vb3; \
        _Pragma("unroll") \
        for (int i = 0; i < 4; i++) { \
            int row_ = w * 16 + 4 * i + g; \
            f32x4 v_ = *(const f32x4*)((char*)pl_ + row_ * 256 + ((c * 16) ^ ((row_ & 7) << 4))); \
            __builtin_nontemporal_store(v_, (f32x4*)(aout + (size_t)(qbase + row_) * SS + (jt) * 64 + c * 4)); \
        } }

    #define CBAR(n) { asm volatile("s_waitcnt vmcnt(" #n ")"); \
                      __builtin_amdgcn_s_barrier(); \
                      __builtin_amdgcn_sched_barrier(0); }

    // ==== sweep 1: row sums + unnormalized ctx (PV), skewed, counted vmcnt ====
    STAGE_K(0, 0);
    if (nj > 1) STAGE_K(1, 1);
    STAGE_V(0, 0);
    CBAR(0);

    float lrow = 0.f;
    f32x4 cacc[4] = {};
    f32x4 sprev[4];

    for (int j = 0; j < nj; j++) {
        if (j + 2 < nj) STAGE_K(j + 2, (j + 2) % 3);
        if (j + 1 < nj) STAGE_V(j + 1, (j + 1) % 3);

        f32x4 scur[4] = {};
        QKT(scur, kb3[j % 3]);

        if (j > 0) {   // finish tile j-1 (always interior: no mask)
            const f16* pvv = vb3[(j - 1) % 3];
            f16x4 bfr[4];
            #pragma unroll
            for (int ni = 0; ni < 4; ni++) {
                float e0 = exp2f(sprev[ni][0] * CSC);
                float e1 = exp2f(sprev[ni][1] * CSC);
                float e2 = exp2f(sprev[ni][2] * CSC);
                float e3 = exp2f(sprev[ni][3] * CSC);
                lrow += e0 + e1 + e2 + e3;
                bfr[ni] = f16x4{ (f16)e0, (f16)e1, (f16)e2, (f16)e3 };
            }
            __builtin_amdgcn_s_setprio(1);
            #pragma unroll
            for (int ni2 = 0; ni2 < 4; ni2++) {
                #pragma unroll
                for (int nk = 0; nk < 4; nk++) {
                    f16x4 av = *(const f16x4*)((const char*)pvv + swz128(ni2 * 16 + c, nk * 32 + g * 8));
                    cacc[ni2] = __builtin_amdgcn_mfma_f32_16x16x16f16(av, bfr[nk], cacc[ni2], 0, 0, 0);
                }
            }
            __builtin_amdgcn_s_setprio(0);
        }

        // counted barrier: allow only this iteration's VMEM ops to stay in flight
        if (j + 3 <= nj)      CBAR(4)    // 2 K-loads + 2 V-loads issued
        else if (j + 2 == nj) CBAR(2)    // only V(nj-1) issued
        else                  CBAR(0);   // last iteration

        #pragma unroll
        for (int x = 0; x < 4; x++) sprev[x] = scur[x];
    }

    // issue sweep-2's K0/K1 early; latency hides under the epilogue VALU
    STAGE_K(0, 0);
    if (nj > 1) STAGE_K(1, 1);

    // epilogue: finish diagonal tile nj-1 (masked)
    {
        const f16* pvv = vb3[(nj - 1) % 3];
        f16x4 bfr[4];
        #pragma unroll
        for (int ni = 0; ni < 4; ni++) {
            int kkb = ni * 16 + 4 * g;
            float e0 = (kkb + 0 > qloc) ? 0.f : exp2f(sprev[ni][0] * CSC);
            float e1 = (kkb + 1 > qloc) ? 0.f : exp2f(sprev[ni][1] * CSC);
            float e2 = (kkb + 2 > qloc) ? 0.f : exp2f(sprev[ni][2] * CSC);
            float e3 = (kkb + 3 > qloc) ? 0.f : exp2f(sprev[ni][3] * CSC);
            lrow += e0 + e1 + e2 + e3;
            bfr[ni] = f16x4{ (f16)e0, (f16)e1, (f16)e2, (f16)e3 };
        }
        __builtin_amdgcn_s_setprio(1);
        #pragma unroll
        for (int ni2 = 0; ni2 < 4; ni2++) {
            #pragma unroll
            for (int nk = 0; nk < 4; nk++) {
                f16x4 av = *(const f16x4*)((const char*)pvv + swz128(ni2 * 16 + c, nk * 32 + g * 8));
                cacc[ni2] = __builtin_amdgcn_mfma_f32_16x16x16f16(av, bfr[nk], cacc[ni2], 0, 0, 0);
            }
        }
        __builtin_amdgcn_s_setprio(0);
    }

    // row-sum reduce across the 4 lane groups (same q = l&15)
    lrow += __shfl_xor(lrow, 16);
    lrow += __shfl_xor(lrow, 32);
    const float rinv = 1.f / lrow;
    const float nls = -__log2f(lrow);

    // store ctx (normalized): lane holds ctx[q=qglob][d = 16*ni2 + 4g + r]
    {
        int b = bh >> 4, h_ = bh & 15;
        f16* cbase = ctx + (size_t)(b * SS + qglob) * DD + h_ * 64;
        #pragma unroll
        for (int ni2 = 0; ni2 < 4; ni2++) {
            f16x4 hv = { (f16)(cacc[ni2][0] * rinv), (f16)(cacc[ni2][1] * rinv),
                         (f16)(cacc[ni2][2] * rinv), (f16)(cacc[ni2][3] * rinv) };
            *(f16x4*)(cbase + ni2 * 16 + 4 * g) = hv;
        }
    }

    CBAR(0);   // K0/K1 ready; all sweep-1 vb3 reads done before pl reuse

    // ==== sweep 2: normalized prob store stream, skewed, LDS-transposed stores ====
    {
        float* pl = (float*)vb3;   // 16 KB: [64 rows][256B] swizzled, wave-local quadrants
        for (int j = 0; j < nj; j++) {
            if (j + 2 < nj) STAGE_K(j + 2, (j + 2) % 3);

            f32x4 scur[4] = {};
            QKT(scur, kb3[j % 3]);

            if (j > 0) {   // store tile j-1 (interior: no mask)
                #pragma unroll
                for (int ni = 0; ni < 4; ni++) {
                    f32x4 st = { exp2f(fmaf(sprev[ni][0], CSC, nls)),
                                 exp2f(fmaf(sprev[ni][1], CSC, nls)),
                                 exp2f(fmaf(sprev[ni][2], CSC, nls)),
                                 exp2f(fmaf(sprev[ni][3], CSC, nls)) };
                    *(f32x4*)((char*)pl + (w * 16 + c) * 256 + ((ni * 64 + g * 16) ^ ((c & 7) << 4))) = st;
                }
                PSTORE(j - 1);
            }

            // counted barrier: this iter's ops = K-loads(2) and/or NT stores(4)
            if (j == 0 && j + 2 < nj)  CBAR(2)
            else if (j + 2 < nj)       CBAR(6)
            else if (j > 0)            CBAR(4)
            else                       CBAR(0);

            #pragma unroll
            for (int x = 0; x < 4; x++) sprev[x] = scur[x];
        }

        // epilogue: store diagonal tile nj-1 (masked); pl is wave-local
        {
            #pragma unroll
            for (int ni = 0; ni < 4; ni++) {
                int kkb = ni * 16 + 4 * g;
                f32x4 st = { (kkb + 0 > qloc) ? 0.f : exp2f(fmaf(sprev[ni][0], CSC, nls)),
                             (kkb + 1 > qloc) ? 0.f : exp2f(fmaf(sprev[ni][1], CSC, nls)),
                             (kkb + 2 > qloc) ? 0.f : exp2f(fmaf(sprev[ni][2], CSC, nls)),
                             (kkb + 3 > qloc) ? 0.f : exp2f(fmaf(sprev[ni][3], CSC, nls)) };
                *(f32x4*)((char*)pl + (w * 16 + c) * 256 + ((ni * 64 + g * 16) ^ ((c & 7) << 4))) = st;
            }
            PSTORE(nj - 1);
        }
    }

    // zero this row-strip's strictly-upper blocks (dense: 4 rows x 256B per instr)
    {
        f32x4 z = { 0.f, 0.f, 0.f, 0.f };
        for (int jb = qb + 1; jb < 32; jb++) {
            #pragma unroll
            for (int i = 0; i < 4; i++) {
                int c2 = t + 256 * i;
                int row = c2 >> 4, cg = c2 & 15;
                __builtin_nontemporal_store(z, (f32x4*)(aout + (size_t)(qbase + row) * SS + jb * 64 + cg * 4));
            }
        }
    }
    #undef STAGE_K
    #undef STAGE_V
    #undef QKT
    #undef PSTORE
    #undef CBAR
}

// ---------------------------------------------------------------------------
// Output projection (pure f16, 2-phase dbuf counted pipeline): ctx.Wo^T+bo+resid
// Epilogue via 64KB LDS transpose -> dense loads; OUTPUT IS F16 (LN input).
// ---------------------------------------------------------------------------
__global__ __launch_bounds__(256) void oproj_gemm(
    const f16* __restrict__ A, const f16* __restrict__ Wof, const float* __restrict__ bo,
    const float* __restrict__ resid, f16* __restrict__ out)
{
    const int m0 = blockIdx.y * 128, n0 = blockIdx.x * 128;
    __shared__ f16 smem[4][128 * 64];   // a dbuf = smem[0..1], b dbuf = smem[2..3]
    const int t = threadIdx.x;
    const int l = t & 63, w = t >> 6;
    const int c = l & 15, g = l >> 4;
    const int wr = (w >> 1) * 64, wc = (w & 1) * 64;

    f32x4 acc[4][4] = {};

    #define OP_STAGE(kt, buf) { \
        _Pragma("unroll") \
        for (int p = 0; p < 4; p++) { \
            int idx = w * 4 + p; \
            int gci = idx * 64 + l; \
            int row = gci >> 3, slot = gci & 7; \
            int ss = slot ^ (row & 7); \
            gl_lds16(A + (size_t)(m0 + row) * DD + (kt) * 64 + ss * 8, smem[buf] + idx * 512); \
            gl_lds16(Wof + (size_t)(n0 + row) * DD + (kt) * 64 + ss * 8, smem[2 + (buf)] + idx * 512); \
        } }

    OP_STAGE(0, 0);
    for (int k0 = 0; k0 < 16; k0++) {
        asm volatile("s_waitcnt vmcnt(0)");
        __builtin_amdgcn_s_barrier();
        __builtin_amdgcn_sched_barrier(0);
        if (k0 + 1 < 16) OP_STAGE(k0 + 1, (k0 + 1) & 1);
        const f16* al = smem[k0 & 1];
        const f16* bl = smem[2 + (k0 & 1)];
        #pragma unroll
        for (int kk = 0; kk < 2; kk++) {
            f16x8 af[4], bf[4];
            #pragma unroll
            for (int mi = 0; mi < 4; mi++) {
                int row = wr + mi * 16 + c;
                af[mi] = *(const f16x8*)((const char*)al + swz128(row, kk * 64 + g * 16));
            }
            #pragma unroll
            for (int ni = 0; ni < 4; ni++) {
                int row = wc + ni * 16 + c;
                bf[ni] = *(const f16x8*)((const char*)bl + swz128(row, kk * 64 + g * 16));
            }
            __builtin_amdgcn_s_setprio(1);
            #pragma unroll
            for (int mi = 0; mi < 4; mi++)
                #pragma unroll
                for (int ni = 0; ni < 4; ni++)
                    acc[mi][ni] = __builtin_amdgcn_mfma_f32_16x16x32_f16(af[mi], bf[ni], acc[mi][ni], 0, 0, 0);
            __builtin_amdgcn_s_setprio(0);
        }
    }
    #undef OP_STAGE

    // epilogue: acc -> 64KB LDS [m 128][n 512B] f32 (swizzled) -> dense f16x4 out
    __syncthreads();
    float* tb = (float*)smem;
    #pragma unroll
    for (int mi = 0; mi < 4; mi++) {
        #pragma unroll
        for (int ni = 0; ni < 4; ni++) {
            int nl = wc + ni * 16 + c;
            #pragma unroll
            for (int r = 0; r < 4; r++) {
                int ml = wr + mi * 16 + g * 4 + r;
                *(float*)((char*)tb + ml * 512 + ((nl * 4) ^ ((ml & 7) << 4))) = acc[mi][ni][r];
            }
        }
    }
    __syncthreads();
    #pragma unroll
    for (int i = 0; i < 16; i++) {
        int o = w * 16384 + i * 1024 + l * 16;   // byte offset into 64 KB
        int row = o >> 9, inb = o & 511;
        f32x4 v = *(const f32x4*)((char*)tb + row * 512 + (inb ^ ((row & 7) << 4)));
        int nl = inb / 4;
        int n = n0 + nl, m = m0 + row;
        f32x4 bo4 = *(const f32x4*)(bo + n);
        f32x4 rs4 = *(const f32x4*)(resid + (size_t)m * DD + n);
        v = v + bo4 + rs4;
        f16x4 hv = { (f16)v.x, (f16)v.y, (f16)v.z, (f16)v.w };
        *(f16x4*)(out + (size_t)m * DD + n) = hv;
    }
}

// ---------------------------------------------------------------------------
// Row LayerNorm: one block per row of 1024; f16 input, f32 output
// ---------------------------------------------------------------------------
__global__ __launch_bounds__(256) void ln_kernel(
    const f16* __restrict__ x, const float* __restrict__ gamma,
    const float* __restrict__ beta, float* __restrict__ out)
{
    int row = blockIdx.x;
    int t = threadIdx.x;
    f16x4 xv = ((const f16x4*)(x + (size_t)row * DD))[t];
    float4 v = { (float)xv[0], (float)xv[1], (float)xv[2], (float)xv[3] };
    float s = v.x + v.y + v.z + v.w;
    __shared__ float red[4];
    #pragma unroll
    for (int o = 32; o; o >>= 1) s += __shfl_down(s, o, 64);
    if ((t & 63) == 0) red[t >> 6] = s;
    __syncthreads();
    float mean = (red[0] + red[1] + red[2] + red[3]) * (1.f / DD);
    __syncthreads();
    float4 d;
    d.x = v.x - mean; d.y = v.y - mean; d.z = v.z - mean; d.w = v.w - mean;
    float q = d.x * d.x + d.y * d.y + d.z * d.z + d.w * d.w;
    #pragma unroll
    for (int o = 32; o; o >>= 1) q += __shfl_down(q, o, 64);
    if ((t & 63) == 0) red[t >> 6] = q;
    __syncthreads();
    float var = (red[0] + red[1] + red[2] + red[3]) * (1.f / DD);
    float rstd = rsqrtf(var + EPSF);
    float4 g = ((const float4*)gamma)[t];
    float4 bt = ((const float4*)beta)[t];
    float4 o4;
    o4.x = d.x * rstd * g.x + bt.x;
    o4.y = d.y * rstd * g.y + bt.y;
    o4.z = d.z * rstd * g.z + bt.z;
    o4.w = d.w * rstd * g.w + bt.w;
    ((float4*)(out + (size_t)row * DD))[t] = o4;
}

extern "C" void kernel_launch(void* const* d_in, const int* in_sizes, int n_in,
                              void* d_out, int out_size, void* d_ws, size_t ws_size,
                              hipStream_t stream)
{
    const float* Q     = (const float*)d_in[0];
    const float* K     = (const float*)d_in[1];
    const float* V     = (const float*)d_in[2];
    const float* Wq    = (const float*)d_in[4];
    const float* bq    = (const float*)d_in[5];
    const float* Wk    = (const float*)d_in[6];
    const float* bk    = (const float*)d_in[7];
    const float* Wv    = (const float*)d_in[8];
    const float* bv    = (const float*)d_in[9];
    const float* Wo    = (const float*)d_in[10];
    const float* bo    = (const float*)d_in[11];
    const float* gamma = (const float*)d_in[12];
    const float* beta  = (const float*)d_in[13];

    float* out_ln   = (float*)d_out;
    float* attn_out = (float*)d_out + (size_t)BB * SS * DD;

    // transient f16 scratch inside d_out regions that are overwritten later
    f16* Qf  = (f16*)attn_out;
    f16* Kf  = Qf + (size_t)MM * DD;
    f16* Vf  = Kf + (size_t)MM * DD;
    f16* Wqf = (f16*)out_ln;
    f16* Wkf = Wqf + (size_t)DD * DD;
    f16* Wvf = Wkf + (size_t)DD * DD;
    f16* Wof = Wvf + (size_t)DD * DD;

    char* ws = (char*)d_ws;
    f16*   qh    = (f16*)(ws);                        // 8 MB
    f16*   kh    = (f16*)(ws + ((size_t)8  << 20));   // 8 MB
    f16*   vTh   = (f16*)(ws + ((size_t)16 << 20));   // 8 MB
    f16*   ctx   = (f16*)(ws + ((size_t)24 << 20));   // 8 MB
    f16*   oproj = (f16*)(ws + ((size_t)32 << 20));   // 8 MB (f16)

    cvt_pass<<<dim3(512, 4), 256, 0, stream>>>(Q, K, V, Wq, Wk, Wv, Wo,
                                               Qf, Kf, Vf, Wqf, Wkf, Wvf, Wof);
    qkv_gemm<<<dim3(8, 32, 3), 256, 0, stream>>>(Qf, Kf, Vf, Wqf, bq, Wkf, bk, Wvf, bv, qh, kh, vTh);
    attn_kernel<<<dim3(1024), 256, 0, stream>>>(qh, kh, vTh, attn_out, ctx);
    oproj_gemm<<<dim3(8, 32), 256, 0, stream>>>(ctx, Wof, bo, Q, oproj);
    ln_kernel<<<dim3(MM), 256, 0, stream>>>(oproj, gamma, beta, out_ln);
}